// Round 1
// baseline (615.169 us; speedup 1.0000x reference)
//
#include <hip/hip_runtime.h>

// out[b][q] = cos(x[b][q] + w[q]), B=4194304, NQ=24, fp32.
// Memory-bound elementwise: float4 loads/stores, weights in LDS,
// native __cosf (v_cos_f32) — threshold 2e-2 is loose.

#define NQ 24

__global__ __launch_bounds__(256) void qfl_cos_kernel(
    const float* __restrict__ x,
    const float* __restrict__ w,
    float* __restrict__ out,
    unsigned int n4)  // number of float4 groups = B*NQ/4
{
    __shared__ float sw[NQ];
    if (threadIdx.x < NQ) sw[threadIdx.x] = w[threadIdx.x];
    __syncthreads();

    unsigned int i = blockIdx.x * blockDim.x + threadIdx.x;
    if (i >= n4) return;

    // Row length 24 floats = 6 float4s -> weight base = (i % 6) * 4
    unsigned int q = (i % 6u) * 4u;

    const float4 xv = reinterpret_cast<const float4*>(x)[i];
    float4 o;
    o.x = __cosf(xv.x + sw[q + 0]);
    o.y = __cosf(xv.y + sw[q + 1]);
    o.z = __cosf(xv.z + sw[q + 2]);
    o.w = __cosf(xv.w + sw[q + 3]);
    reinterpret_cast<float4*>(out)[i] = o;
}

extern "C" void kernel_launch(void* const* d_in, const int* in_sizes, int n_in,
                              void* d_out, int out_size, void* d_ws, size_t ws_size,
                              hipStream_t stream) {
    const float* x = (const float*)d_in[0];
    const float* w = (const float*)d_in[1];
    float* out = (float*)d_out;

    const unsigned int n = (unsigned int)out_size;   // B*NQ = 100663296, divisible by 4
    const unsigned int n4 = n / 4u;

    const int block = 256;
    const unsigned int grid = (n4 + block - 1) / block;

    qfl_cos_kernel<<<grid, block, 0, stream>>>(x, w, out, n4);
}